// Round 1
// baseline (38.294 us; speedup 1.0000x reference)
//
#include <hip/hip_runtime.h>
#include <math.h>

#define SEQ   32768
#define DENC  200
#define NH    8192

#define NB1   128               // K1 blocks (v partials)
#define ROWS_PER_B (NH / NB1)   // 64 rows of W per block
#define NB2   256               // K2 blocks (energies)
#define NB3   64                // K3 blocks (exp+sum)
#define NB4   64                // K4 blocks (normalize)

// ws layout (floats):
// [0, NB1*DENC)            v partials
#define WS_C   (NB1*DENC)       // [WS_C, WS_C+NB1)    c partials
#define WS_MAX (WS_C + NB1)     // [WS_MAX, WS_MAX+NB2) block maxes
#define WS_SUM (WS_MAX + NB2)   // [WS_SUM, WS_SUM+NB3) block sums

__device__ __forceinline__ float wave_sum(float x) {
    #pragma unroll
    for (int off = 32; off; off >>= 1) x += __shfl_xor(x, off, 64);
    return x;
}
__device__ __forceinline__ float wave_max(float x) {
    #pragma unroll
    for (int off = 32; off; off >>= 1) x = fmaxf(x, __shfl_xor(x, off, 64));
    return x;
}

// K1: partial v[d] = sum over this block's rows of W[h,d]*hidden[h]; partial c.
__global__ __launch_bounds__(256) void k1_proj(const float* __restrict__ W,
                                               const float* __restrict__ hidden,
                                               const float* __restrict__ bias,
                                               float* __restrict__ ws) {
    const int t = threadIdx.x, b = blockIdx.x;
    const int h0 = b * ROWS_PER_B;
    if (t < DENC) {
        float acc = 0.f;
        #pragma unroll 8
        for (int i = 0; i < ROWS_PER_B; ++i) {
            const int h = h0 + i;
            acc = fmaf(W[(size_t)h * DENC + t], hidden[h], acc);
        }
        ws[b * DENC + t] = acc;
    }
    if (t < 64) {   // wave 0 handles the 64 rows' bias partial
        float cp = bias[h0 + t] * hidden[h0 + t];
        cp = wave_sum(cp);
        if (t == 0) ws[WS_C + b] = cp;
    }
}

// K2: energies[s] = enc[s,:].v + c -> d_out; per-block max -> ws.
__global__ __launch_bounds__(256) void k2_energy(const float* __restrict__ enc,
                                                 const float* __restrict__ ws,
                                                 float* __restrict__ out,
                                                 float* __restrict__ ws_out) {
    __shared__ float v_lds[DENC];
    __shared__ float c_lds;
    __shared__ float m_lds[4];
    const int t = threadIdx.x, b = blockIdx.x;

    if (t < DENC) {                       // reduce v partials (L2-resident)
        float a = 0.f;
        #pragma unroll 8
        for (int p = 0; p < NB1; ++p) a += ws[p * DENC + t];
        v_lds[t] = a;
    }
    if (t < 64) {                         // reduce c partials
        float cp = ws[WS_C + t] + ws[WS_C + 64 + t];
        cp = wave_sum(cp);
        if (t == 0) c_lds = cp;
    }
    __syncthreads();

    const int lane = t & 63, wid = t >> 6;
    float4 v4 = make_float4(0.f, 0.f, 0.f, 0.f);
    if (lane < 50) v4 = *(const float4*)(v_lds + lane * 4);
    const float c = c_lds;

    float wmax = -INFINITY;
    const int gw = b * 4 + wid;           // global wave id, 0..NB2*4-1
    const int nwaves = NB2 * 4;
    for (int s = gw; s < SEQ; s += nwaves) {
        float dot = 0.f;
        if (lane < 50) {
            const float4 e4 = *(const float4*)(enc + (size_t)s * DENC + lane * 4);
            dot = e4.x * v4.x + e4.y * v4.y + e4.z * v4.z + e4.w * v4.w;
        }
        dot = wave_sum(dot);
        const float en = dot + c;
        if (lane == 0) out[s] = en;
        wmax = fmaxf(wmax, en);
    }
    if (lane == 0) m_lds[wid] = wmax;
    __syncthreads();
    if (t == 0)
        ws_out[WS_MAX + b] = fmaxf(fmaxf(m_lds[0], m_lds[1]),
                                   fmaxf(m_lds[2], m_lds[3]));
}

// K3: out[i] = exp(out[i]-M) in place; per-block sum -> ws.
__global__ __launch_bounds__(256) void k3_exp(float* __restrict__ out,
                                              const float* __restrict__ ws_in,
                                              float* __restrict__ ws_out) {
    __shared__ float r_lds[4];
    __shared__ float M_s;
    const int t = threadIdx.x, b = blockIdx.x;
    const int lane = t & 63, wid = t >> 6;

    if (t < 64) {                         // reduce NB2=256 maxes: 4 each
        float m = fmaxf(fmaxf(ws_in[WS_MAX + t],       ws_in[WS_MAX + t + 64]),
                        fmaxf(ws_in[WS_MAX + t + 128], ws_in[WS_MAX + t + 192]));
        m = wave_max(m);
        if (t == 0) M_s = m;
    }
    __syncthreads();
    const float M = M_s;

    float acc = 0.f;
    for (int i = b * 256 + t; i < SEQ; i += NB3 * 256) {
        const float x = expf(out[i] - M);
        out[i] = x;
        acc += x;
    }
    acc = wave_sum(acc);
    if (lane == 0) r_lds[wid] = acc;
    __syncthreads();
    if (t == 0)
        ws_out[WS_SUM + b] = r_lds[0] + r_lds[1] + r_lds[2] + r_lds[3];
}

// K4: out[i] *= 1/S.
__global__ __launch_bounds__(256) void k4_norm(float* __restrict__ out,
                                               const float* __restrict__ ws_in) {
    __shared__ float S_s;
    const int t = threadIdx.x, b = blockIdx.x;
    if (t < 64) {                         // reduce NB3=64 sums
        float s = ws_in[WS_SUM + t];
        s = wave_sum(s);
        if (t == 0) S_s = 1.f / s;
    }
    __syncthreads();
    const float inv = S_s;
    for (int i = b * 256 + t; i < SEQ; i += NB4 * 256)
        out[i] *= inv;
}

extern "C" void kernel_launch(void* const* d_in, const int* in_sizes, int n_in,
                              void* d_out, int out_size, void* d_ws, size_t ws_size,
                              hipStream_t stream) {
    const float* hidden = (const float*)d_in[0];   // [H]
    const float* enc    = (const float*)d_in[1];   // [SEQ, DENC]
    const float* W      = (const float*)d_in[2];   // [H, DENC]
    const float* bias   = (const float*)d_in[3];   // [H]
    float* out = (float*)d_out;
    float* ws  = (float*)d_ws;

    k1_proj  <<<NB1, 256, 0, stream>>>(W, hidden, bias, ws);
    k2_energy<<<NB2, 256, 0, stream>>>(enc, ws, out, ws);
    k3_exp   <<<NB3, 256, 0, stream>>>(out, ws, ws);
    k4_norm  <<<NB4, 256, 0, stream>>>(out, ws);
}

// Round 2
// 28.702 us; speedup vs baseline: 1.3342x; 1.3342x over previous
//
#include <hip/hip_runtime.h>
#include <math.h>

#define SEQ   32768
#define DENC  200
#define NH    8192

#define NB1       64                 // K1 blocks
#define TB1       1024
#define ROWS1     (NH / NB1)         // 128 rows of W per block
#define GROUPS1   (TB1 / 256)        // 4 thread-groups per block
#define ROWS_PG   (ROWS1 / GROUPS1)  // 32 rows per group

#define NB2       512                // K2 blocks
#define ROWS2     (SEQ / NB2)        // 64 rows per block
#define ROWS_PW   (ROWS2 / 4)        // 16 rows per wave

#define NB3       (SEQ / 256)        // 128 blocks, 1 elem/thread

// ws layout:
//   double ws_p[SEQ]        exp values
//   double ws_sum[NB2]      per-block exp sums
//   float  ws_v[DENC*NB1]   v partials, TRANSPOSED [d][p]
//   float  ws_c[NB1]        c partials

__device__ __forceinline__ float wave_sum(float x) {
    #pragma unroll
    for (int off = 32; off; off >>= 1) x += __shfl_xor(x, off, 64);
    return x;
}
__device__ __forceinline__ double wave_sum_d(double x) {
    #pragma unroll
    for (int off = 32; off; off >>= 1) x += __shfl_xor(x, off, 64);
    return x;
}

// K1: v partials (64 of them) + c partials.
__global__ __launch_bounds__(TB1) void k1_proj(const float* __restrict__ W,
                                               const float* __restrict__ hidden,
                                               const float* __restrict__ bias,
                                               float* __restrict__ ws_v,
                                               float* __restrict__ ws_c) {
    __shared__ float part[GROUPS1][DENC];
    __shared__ float cpart[2];
    const int t  = threadIdx.x;
    const int g  = t >> 8;            // group 0..3
    const int lt = t & 255;           // 0..255 within group
    const int b  = blockIdx.x;
    const int h0 = b * ROWS1 + g * ROWS_PG;

    if (lt < DENC) {
        float acc = 0.f;
        #pragma unroll
        for (int i = 0; i < ROWS_PG; ++i)
            acc = fmaf(W[(size_t)(h0 + i) * DENC + lt], hidden[h0 + i], acc);
        part[g][lt] = acc;
    }
    // bias partial over this block's 128 rows: waves 0,1
    float cp = 0.f;
    if (t < ROWS1) cp = bias[b * ROWS1 + t] * hidden[b * ROWS1 + t];
    cp = wave_sum(cp);
    const int lane = t & 63, wid = t >> 6;
    if (wid < 2 && lane == 0) cpart[wid] = cp;
    __syncthreads();

    if (t < DENC)
        ws_v[t * NB1 + b] = part[0][t] + part[1][t] + part[2][t] + part[3][t];
    if (t == 0)
        ws_c[b] = cpart[0] + cpart[1];
}

// K2: reduce v, energies, exp (double, no max needed), per-block sums.
__global__ __launch_bounds__(256) void k2_energy(const float* __restrict__ enc,
                                                 const float* __restrict__ ws_v,
                                                 const float* __restrict__ ws_c,
                                                 double* __restrict__ ws_p,
                                                 double* __restrict__ ws_sum) {
    __shared__ float  v_lds[DENC];
    __shared__ float  c_lds;
    __shared__ double s_lds[4];
    const int t = threadIdx.x, b = blockIdx.x;
    const int lane = t & 63, wid = t >> 6;

    if (t < DENC) {
        float a = 0.f;
        const float* p = ws_v + t * NB1;
        #pragma unroll
        for (int i = 0; i < NB1; ++i) a += p[i];
        v_lds[t] = a;
    }
    if (t < NB1) {
        float cp = ws_c[t];
        cp = wave_sum(cp);
        if (t == 0) c_lds = cp;
    }
    __syncthreads();

    float4 v4 = make_float4(0.f, 0.f, 0.f, 0.f);
    if (lane < 50) v4 = *(const float4*)(v_lds + lane * 4);
    const float c = c_lds;

    double acc = 0.0;
    const int s0 = b * ROWS2 + wid * ROWS_PW;   // contiguous 16-row span per wave
    #pragma unroll 4
    for (int i = 0; i < ROWS_PW; ++i) {
        const int s = s0 + i;
        float dot = 0.f;
        if (lane < 50) {
            const float4 e4 = *(const float4*)(enc + (size_t)s * DENC + lane * 4);
            dot = e4.x * v4.x + e4.y * v4.y + e4.z * v4.z + e4.w * v4.w;
        }
        dot = wave_sum(dot);                    // all lanes hold the sum
        const double p = exp((double)(dot + c));
        if (lane == 0) { ws_p[s] = p; acc += p; }
    }
    if (lane == 0) s_lds[wid] = acc;
    __syncthreads();
    if (t == 0) ws_sum[b] = s_lds[0] + s_lds[1] + s_lds[2] + s_lds[3];
}

// K3: reduce sums, normalize, write output.
__global__ __launch_bounds__(256) void k3_norm(const double* __restrict__ ws_p,
                                               const double* __restrict__ ws_sum,
                                               float* __restrict__ out) {
    __shared__ double r_lds[4];
    __shared__ double inv_lds;
    const int t = threadIdx.x, b = blockIdx.x;
    const int lane = t & 63, wid = t >> 6;

    double a = ws_sum[t] + ws_sum[t + 256];     // NB2=512 -> 2 per thread
    a = wave_sum_d(a);
    if (lane == 0) r_lds[wid] = a;
    __syncthreads();
    if (t == 0) inv_lds = 1.0 / (r_lds[0] + r_lds[1] + r_lds[2] + r_lds[3]);
    __syncthreads();

    const double inv = inv_lds;
    const int i = b * 256 + t;
    out[i] = (float)(ws_p[i] * inv);
}

extern "C" void kernel_launch(void* const* d_in, const int* in_sizes, int n_in,
                              void* d_out, int out_size, void* d_ws, size_t ws_size,
                              hipStream_t stream) {
    const float* hidden = (const float*)d_in[0];   // [H]
    const float* enc    = (const float*)d_in[1];   // [SEQ, DENC]
    const float* W      = (const float*)d_in[2];   // [H, 200]
    const float* bias   = (const float*)d_in[3];   // [H]
    float* out = (float*)d_out;

    double* ws_p   = (double*)d_ws;                // SEQ doubles
    double* ws_sum = ws_p + SEQ;                   // NB2 doubles
    float*  ws_v   = (float*)(ws_sum + NB2);       // DENC*NB1 floats
    float*  ws_c   = ws_v + DENC * NB1;            // NB1 floats

    k1_proj  <<<NB1, TB1, 0, stream>>>(W, hidden, bias, ws_v, ws_c);
    k2_energy<<<NB2, 256, 0, stream>>>(enc, ws_v, ws_c, ws_p, ws_sum);
    k3_norm  <<<NB3, 256, 0, stream>>>(ws_p, ws_sum, out);
}